// Round 1
// 273.756 us; speedup vs baseline: 1.0582x; 1.0582x over previous
//
#include <hip/hip_runtime.h>

#define T_LEN 256
#define D_IN 4
#define SPR 8                       // timesteps per barrier round
#define NROUND (T_LEN / SPR + 2)    // 34: layer skew 0..2

typedef __fp16 h8 __attribute__((ext_vector_type(8)));
typedef __fp16 cvt2_t __attribute__((ext_vector_type(2)));
typedef float float4v __attribute__((ext_vector_type(4)));

struct CellW { const float *Wih, *Whh, *bih, *bhh; };
struct Params { CellW c[6]; const float* y; float* hout; };

__device__ __forceinline__ float fexp2(float x) { return __builtin_amdgcn_exp2f(x); }
__device__ __forceinline__ float frcp(float x)  { return __builtin_amdgcn_rcpf(x); }
__device__ __forceinline__ int packh(float a, float b) {
    cvt2_t p = __builtin_amdgcn_cvt_pkrtz(a, b);
    return __builtin_bit_cast(int, p);
}
__device__ __forceinline__ h8 mk8(int a, int b, int c, int d) {
    int4 v; v.x = a; v.y = b; v.z = c; v.w = d;
    return __builtin_bit_cast(h8, v);
}

// K=32 MFMA: one instruction per gate. A = [Whh-cols | Wprev-cols] with the
// SAME per-lane element convention used for B = {own-h packs, prev packs}.
// A/B share the lane->k mapping on 16x16 MFMAs, so this is correct for any
// hardware k-ordering (contiguous-8 or split 4+4). D layout unchanged:
// lane(n,Q) reg r = row 4Q+r, col n  ->  recurrence still needs only 2 packs.
#define MFMA32(a, b, c) __builtin_amdgcn_mfma_f32_16x16x32_f16(a, b, c, 0, 0, 0)

// Activation for the lane's 4 units. pi,pf,po pre-scaled by -log2e, pg by
// -2log2e (folded into A/bias). 5 exp2 per unit (irreducible) but rcps are
// PAIRED across the 4 independent unit chains: rcp(a),rcp(b) ->
// R=rcp(a*b); 1/a=R*b; 1/b=R*a.  12 -> 6 rcps per lane-step.
// Overflow audit (|pre| <= ~10.5 from weight bounds): F<=2^16, P<=2^47,
// Dh<=2^46 (ec clamped at 2^30); all pair products < 2^94 << 2^127.
__device__ __forceinline__ void act4(const float4v& pi, const float4v& pf,
                                     const float4v& pg, const float4v& po,
                                     float* cc, float* h) {
    float F[4], P[4], NG[4];
#pragma unroll
    for (int j = 0; j < 4; ++j) {
        float ei = fexp2(pi[j]);
        float ef = fexp2(pf[j]);
        float eg = fexp2(pg[j]);
        F[j]  = 1.f + ef;                      // sigmoid(f) denominator
        P[j]  = (1.f + ei) * (1.f + eg);       // i*g joint denominator
        NG[j] = 1.f - eg;                      // tanh(g) numerator
    }
    float RF01 = frcp(F[0] * F[1]);
    float RF23 = frcp(F[2] * F[3]);
    float RP01 = frcp(P[0] * P[1]);
    float RP23 = frcp(P[2] * P[3]);
    float f0 = RF01 * F[1], f1 = RF01 * F[0];
    float f2 = RF23 * F[3], f3 = RF23 * F[2];
    float ig0 = NG[0] * P[1] * RP01, ig1 = NG[1] * P[0] * RP01;
    float ig2 = NG[2] * P[3] * RP23, ig3 = NG[3] * P[2] * RP23;

    float NO[4], Dh[4];
    float cn0 = fmaf(f0, cc[0], ig0); cc[0] = cn0;
    float cn1 = fmaf(f1, cc[1], ig1); cc[1] = cn1;
    float cn2 = fmaf(f2, cc[2], ig2); cc[2] = cn2;
    float cn3 = fmaf(f3, cc[3], ig3); cc[3] = cn3;
    const float K2 = -2.8853900817779268f;     // -2*log2e
#pragma unroll
    for (int j = 0; j < 4; ++j) {
        float cn = cc[j];
        float eo = fexp2(po[j]);
        // clamp 30 (was 80): keeps paired Dh product finite; err < 2^-29
        float ec = fexp2(fminf(cn * K2, 30.f));
        NO[j] = 1.f - ec;
        Dh[j] = (1.f + eo) * (1.f + ec);
    }
    float RH01 = frcp(Dh[0] * Dh[1]);
    float RH23 = frcp(Dh[2] * Dh[3]);
    h[0] = NO[0] * Dh[1] * RH01;
    h[1] = NO[1] * Dh[0] * RH01;
    h[2] = NO[2] * Dh[3] * RH23;
    h[3] = NO[3] * Dh[2] * RH23;
}

// Block = 3 waves = 3 layers of one 16-chain tile, skewed by 1 round.
// Cross-layer h: verbatim per-lane int2 copy via parity LDS slabs.
// Own recurrence: in-register (B-layout == D-layout). x: registers only.
__global__ void __launch_bounds__(192)
__attribute__((amdgpu_waves_per_eu(1, 2)))
lstm_chain_kernel(Params p)
{
    __shared__ int2 lds_h[2][2][SPR][64];   // [producer][parity][k][lane] 16KB

    const int w = threadIdx.x >> 6;     // wave = layer
    const int L = threadIdx.x & 63;
    const int n = L & 15;               // batch col
    const int Q = L >> 4;

    const int tid = blockIdx.x;
    const int dir = tid & 1;
    const int b0  = (tid >> 1) * 16;

    const CellW cw = p.c[dir * 3 + w];
    const float LOG2E = 1.4426950408889634f;

    // ---- fused A-frags: elems 0-3 = Whh k=4Q..4Q+3, elems 4-7 = prev-side
    // (Wih cols for w>0; x-weights (Q==0) / zero for w==0). Scale folded. ----
    h8 A8[4];
    float4v bs[4];
#pragma unroll
    for (int g = 0; g < 4; ++g) {
        const float s = (g == 2) ? -2.f * LOG2E : -LOG2E;
        const int row = g * 16 + n;
        float vh[4], vp[4];
#pragma unroll
        for (int i = 0; i < 4; ++i) {
            const int k = 4 * Q + i;
            vh[i] = cw.Whh[row * 16 + k];
            vp[i] = (w == 0) ? ((Q == 0) ? cw.Wih[row * D_IN + k] : 0.f)
                             : cw.Wih[row * 16 + k];
        }
        A8[g] = mk8(packh(vh[0] * s, vh[1] * s), packh(vh[2] * s, vh[3] * s),
                    packh(vp[0] * s, vp[1] * s), packh(vp[2] * s, vp[3] * s));
        const int u0 = g * 16 + 4 * Q;   // bias: reg r -> unit 4Q+r
        float4 bi = *(const float4*)&cw.bih[u0];
        float4 bh = *(const float4*)&cw.bhh[u0];
        bs[g] = (float4v){(bi.x+bh.x)*s, (bi.y+bh.y)*s, (bi.z+bh.z)*s, (bi.w+bh.w)*s};
    }

    // ---- x prefetch (wave 0, lanes L<16 = chain n); fed straight into B ----
    const float* ybase = p.y + (size_t)b0 * (T_LEN * D_IN);
    float4 xn[SPR];
    if (w == 0 && L < 16) {
#pragma unroll
        for (int k = 0; k < SPR; ++k) {
            const int tt = dir ? (T_LEN - 1 - k) : k;
            xn[k] = *(const float4*)(ybase + ((size_t)n * T_LEN + tt) * D_IN);
        }
    }

    float cc[4] = {0.f, 0.f, 0.f, 0.f};
    float h[4] = {0.f, 0.f, 0.f, 0.f};
    int hp0 = 0, hp1 = 0;               // packed own h (B elems 0-3 verbatim)

#pragma unroll 1
    for (int s = 0; s < NROUND; ++s) {
        __syncthreads();
        const int t0 = (s - w) * SPR;
        if (t0 < 0 || t0 >= T_LEN) continue;

        // wave 0: commit prefetched x to packed B-dwords, start next loads
        int xp[SPR][2];
        if (w == 0) {
            if (L < 16) {
#pragma unroll
                for (int k = 0; k < SPR; ++k) {
                    xp[k][0] = packh(xn[k].x, xn[k].y);
                    xp[k][1] = packh(xn[k].z, xn[k].w);
                }
                if (t0 + SPR < T_LEN) {
#pragma unroll
                    for (int k = 0; k < SPR; ++k) {
                        const int t = t0 + SPR + k;
                        const int tt = dir ? (T_LEN - 1 - t) : t;
                        xn[k] = *(const float4*)(ybase + ((size_t)n * T_LEN + tt) * D_IN);
                    }
                }
            } else {
#pragma unroll
                for (int k = 0; k < SPR; ++k) { xp[k][0] = 0; xp[k][1] = 0; }
            }
        }

        // hoist all cross-layer h reads (latency off the chain)
        int2 hv[SPR];
        if (w >= 1) {
#pragma unroll
            for (int k = 0; k < SPR; ++k)
                hv[k] = lds_h[w - 1][(s + 1) & 1][k][L];
        }

#pragma unroll
        for (int k = 0; k < SPR; ++k) {
            const int pd0 = (w == 0) ? xp[k][0] : hv[k].x;
            const int pd1 = (w == 0) ? xp[k][1] : hv[k].y;
            const h8 b8 = mk8(hp0, hp1, pd0, pd1);
            float4v pi = MFMA32(A8[0], b8, bs[0]);
            float4v pf = MFMA32(A8[1], b8, bs[1]);
            float4v pg = MFMA32(A8[2], b8, bs[2]);
            float4v po = MFMA32(A8[3], b8, bs[3]);
            act4(pi, pf, pg, po, cc, h);
            hp0 = packh(h[0], h[1]);
            hp1 = packh(h[2], h[3]);
            if (w < 2) {
                int2 hw; hw.x = hp0; hw.y = hp1;
                lds_h[w][s & 1][k][L] = hw;
            }
        }
    }

    // wave 2 holds h3(T-1): lane (n,Q) has units 4Q..4Q+3, batch n
    if (w == 2) {
        float4v ho = {h[0], h[1], h[2], h[3]};
        *(float4v*)&p.hout[(size_t)(b0 + n) * 32 + dir * 16 + 4 * Q] = ho;
    }
}

__global__ void out_proj_kernel(const float* __restrict__ ws,
                                const float* __restrict__ Wout,
                                const float* __restrict__ bout,
                                float* __restrict__ out, int B)
{
    int idx = blockIdx.x * blockDim.x + threadIdx.x;
    if (idx >= B * 4) return;
    int b = idx >> 2, o = idx & 3;
    float acc = bout[o];
    const float* h = ws + (size_t)b * 32;
    const float* w = Wout + o * 32;
#pragma unroll
    for (int m = 0; m < 32; ++m) acc = fmaf(h[m], w[m], acc);
    out[idx] = acc;
}

extern "C" void kernel_launch(void* const* d_in, const int* in_sizes, int n_in,
                              void* d_out, int out_size, void* d_ws, size_t ws_size,
                              hipStream_t stream)
{
    const int B = in_sizes[0] / (T_LEN * D_IN); // 4096

    Params p;
    for (int s = 0; s < 6; ++s) {
        p.c[s].Wih = (const float*)d_in[1 + 4 * s];
        p.c[s].Whh = (const float*)d_in[2 + 4 * s];
        p.c[s].bih = (const float*)d_in[3 + 4 * s];
        p.c[s].bhh = (const float*)d_in[4 + 4 * s];
    }
    p.y = (const float*)d_in[0];
    p.hout = (float*)d_ws;

    const int tiles = (B / 16) * 2;          // 16 chains per tile, both dirs
    lstm_chain_kernel<<<tiles, 192, 0, stream>>>(p);

    const float* Wout = (const float*)d_in[25];
    const float* bout = (const float*)d_in[26];
    out_proj_kernel<<<(B * 4 + 255) / 256, 256, 0, stream>>>(
        (const float*)d_ws, Wout, bout, (float*)d_out, B);
}